// Round 4
// baseline (882.673 us; speedup 1.0000x reference)
//
#include <hip/hip_runtime.h>

#define HIDDEN 4096
#define NHEADS 32
#define NKV 8
#define HD 128
#define KVD 1024
#define QKVN 6144
#define SEQ 2048

typedef unsigned short u16;
typedef __bf16 bf16x8 __attribute__((ext_vector_type(8)));
typedef float f32x4 __attribute__((ext_vector_type(4)));
typedef unsigned short u16x4 __attribute__((ext_vector_type(4)));

__device__ __forceinline__ u16 f2b(float f) {
  union { float f; unsigned u; } v; v.f = f;
  unsigned r = (v.u + 0x7fffu + ((v.u >> 16) & 1u)) >> 16;
  return (u16)r;
}

__device__ __forceinline__ void gl_lds16(const void* g, void* l) {
  __builtin_amdgcn_global_load_lds(
      (const __attribute__((address_space(1))) unsigned*)g,
      (__attribute__((address_space(3))) unsigned*)l, 16, 0, 0);
}

__device__ __forceinline__ f32x4 mfma16(bf16x8 a, bf16x8 b, f32x4 c) {
  return __builtin_amdgcn_mfma_f32_16x16x32_bf16(a, b, c, 0, 0, 0);
}

// ---------------- f32 -> bf16 convert ----------------
__global__ void cvt_bf16(const float* __restrict__ x, u16* __restrict__ y, int n) {
  int i = (blockIdx.x * 256 + threadIdx.x) * 4;
  if (i < n) {
    float4 v = *(const float4*)(x + i);
    u16x4 o = {f2b(v.x), f2b(v.y), f2b(v.z), f2b(v.w)};
    *(u16x4*)(y + i) = o;
  }
}

// ---------------- 64x64 tiled transpose + f32->bf16, vectorized ----------------
__global__ void transpose_cvt64(const float* __restrict__ W, long ldW,
                                u16* __restrict__ Wt, long ldT) {
  __shared__ float tile[64][65];
  long c0 = blockIdx.x * 64L, r0 = blockIdx.y * 64L;
  int tx = threadIdx.x, ty = threadIdx.y;
#pragma unroll
  for (int i = 0; i < 4; ++i) {
    float4 v = *(const float4*)(W + (r0 + ty + i * 16) * ldW + c0 + tx * 4);
    tile[ty + i * 16][tx * 4 + 0] = v.x;
    tile[ty + i * 16][tx * 4 + 1] = v.y;
    tile[ty + i * 16][tx * 4 + 2] = v.z;
    tile[ty + i * 16][tx * 4 + 3] = v.w;
  }
  __syncthreads();
#pragma unroll
  for (int i = 0; i < 4; ++i) {
    int c = ty + i * 16;
    u16x4 o = {f2b(tile[tx * 4 + 0][c]), f2b(tile[tx * 4 + 1][c]),
               f2b(tile[tx * 4 + 2][c]), f2b(tile[tx * 4 + 3][c])};
    *(u16x4*)(Wt + (c0 + c) * ldT + r0 + tx * 4) = o;
  }
}

// ---------------- m97-style bf16 GEMM: C = A[M,K] * Bt[N,K]^T + bias ----------------
__global__ __launch_bounds__(256) void gemm_bt_bias(
    const u16* __restrict__ A, const u16* __restrict__ Bt,
    const float* __restrict__ bias, float* __restrict__ C,
    int M, int N, int K) {
  __shared__ u16 As[128 * 32];
  __shared__ u16 Bs[128 * 32];
  const int t = threadIdx.x;
  const int w = t >> 6, lane = t & 63, quad = lane >> 4, l15 = lane & 15;
  const int wy = w >> 1, wx = w & 1;
  const long m0 = blockIdx.y * 128L, n0 = blockIdx.x * 128L;
  f32x4 acc[4][4] = {};
  const u16* Ag = A + (m0 + (t >> 2)) * (long)K + (t & 3) * 8;
  const u16* Bg = Bt + (n0 + (t >> 2)) * (long)K + (t & 3) * 8;
  char* lA0 = (char*)As + w * 1024;
  char* lA1 = (char*)As + 4096 + w * 1024;
  char* lB0 = (char*)Bs + w * 1024;
  char* lB1 = (char*)Bs + 4096 + w * 1024;
  const long k64 = 64L * K;
  for (int k0 = 0; k0 < K; k0 += 32) {
    gl_lds16(Ag + k0, lA0);
    gl_lds16(Ag + k64 + k0, lA1);
    gl_lds16(Bg + k0, lB0);
    gl_lds16(Bg + k64 + k0, lB1);
    __syncthreads();
    bf16x8 af[4], bfr[4];
#pragma unroll
    for (int mi = 0; mi < 4; ++mi)
      af[mi] = *reinterpret_cast<const bf16x8*>(&As[(wy * 64 + mi * 16 + l15) * 32 + quad * 8]);
#pragma unroll
    for (int nj = 0; nj < 4; ++nj)
      bfr[nj] = *reinterpret_cast<const bf16x8*>(&Bs[(wx * 64 + nj * 16 + l15) * 32 + quad * 8]);
#pragma unroll
    for (int mi = 0; mi < 4; ++mi)
#pragma unroll
      for (int nj = 0; nj < 4; ++nj)
        acc[mi][nj] = mfma16(af[mi], bfr[nj], acc[mi][nj]);
    __syncthreads();
  }
#pragma unroll
  for (int mi = 0; mi < 4; ++mi) {
#pragma unroll
    for (int nj = 0; nj < 4; ++nj) {
      long n = n0 + wx * 64 + nj * 16 + l15;
      float bv = bias[n];
      long mrow = m0 + wy * 64 + mi * 16 + quad * 4;
#pragma unroll
      for (int r = 0; r < 4; ++r)
        C[(mrow + r) * (long)N + n] = acc[mi][nj][r] + bv;
    }
  }
}

// ---------------- fused QKV GEMM + bias + RoPE + Q-scale + V-transpose ----------------
// Identical 4x4 wave layout / K-loop as gemm_bt_bias (VGPR 80, 6 blocks/CU).
// Epilogue: Q/K head tiles exchange the (d, d+64) RoPE halves across the wx
// wave pair through a padded LDS buffer (reusing the staging LDS); V tiles
// store transposed into Vt[kvh][d][s].
__global__ __launch_bounds__(256) void gemm_qkv(
    const u16* __restrict__ A, const u16* __restrict__ Bt,
    const float* __restrict__ bias, const int* __restrict__ pos,
    u16* __restrict__ Qr, u16* __restrict__ Kr, u16* __restrict__ Vt) {
  __shared__ union {
    struct { u16 As[128 * 32]; u16 Bs[128 * 32]; } g;
    float xb[2][16][130];  // [wy][row in mi-block][col 0..127], pad->130 (2-way banks: free)
  } sm;
  const int K = HIDDEN;
  const int t = threadIdx.x;
  const int w = t >> 6, lane = t & 63, quad = lane >> 4, l15 = lane & 15;
  const int wy = w >> 1, wx = w & 1;
  const long m0 = blockIdx.y * 128L, n0 = blockIdx.x * 128L;
  f32x4 acc[4][4] = {};
  const u16* Ag = A + (m0 + (t >> 2)) * (long)K + (t & 3) * 8;
  const u16* Bg = Bt + (n0 + (t >> 2)) * (long)K + (t & 3) * 8;
  char* lA0 = (char*)sm.g.As + w * 1024;
  char* lA1 = (char*)sm.g.As + 4096 + w * 1024;
  char* lB0 = (char*)sm.g.Bs + w * 1024;
  char* lB1 = (char*)sm.g.Bs + 4096 + w * 1024;
  const long k64 = 64L * K;
  for (int k0 = 0; k0 < K; k0 += 32) {
    gl_lds16(Ag + k0, lA0);
    gl_lds16(Ag + k64 + k0, lA1);
    gl_lds16(Bg + k0, lB0);
    gl_lds16(Bg + k64 + k0, lB1);
    __syncthreads();
    bf16x8 af[4], bfr[4];
#pragma unroll
    for (int mi = 0; mi < 4; ++mi)
      af[mi] = *reinterpret_cast<const bf16x8*>(&sm.g.As[(wy * 64 + mi * 16 + l15) * 32 + quad * 8]);
#pragma unroll
    for (int nj = 0; nj < 4; ++nj)
      bfr[nj] = *reinterpret_cast<const bf16x8*>(&sm.g.Bs[(wx * 64 + nj * 16 + l15) * 32 + quad * 8]);
#pragma unroll
    for (int mi = 0; mi < 4; ++mi)
#pragma unroll
      for (int nj = 0; nj < 4; ++nj)
        acc[mi][nj] = mfma16(af[mi], bfr[nj], acc[mi][nj]);
    __syncthreads();
  }

  const int tile = (int)(n0 >> 7);  // head index 0..47
  float bv[4];
#pragma unroll
  for (int nj = 0; nj < 4; ++nj) bv[nj] = bias[n0 + wx * 64 + nj * 16 + l15];

  if (tile >= 40) {
    // V head: store transposed into Vt[kvh][d][s], 4 consecutive s packed.
    const int kvh = tile - 40;
    u16* outp = Vt + (long)kvh * HD * SEQ;
#pragma unroll
    for (int mi = 0; mi < 4; ++mi) {
      long s_base = m0 + wy * 64 + mi * 16 + quad * 4;
#pragma unroll
      for (int nj = 0; nj < 4; ++nj) {
        int d = wx * 64 + nj * 16 + l15;
        u16x4 o = {f2b(acc[mi][nj][0] + bv[nj]), f2b(acc[mi][nj][1] + bv[nj]),
                   f2b(acc[mi][nj][2] + bv[nj]), f2b(acc[mi][nj][3] + bv[nj])};
        *(u16x4*)(outp + (long)d * SEQ + s_base) = o;
      }
    }
  } else {
    // Q or K head: RoPE. wx=0 holds x1 (d<64), wx=1 holds x2 (d>=64); freq
    // index j = nj*16+l15 for both. Exchange partner half via LDS, per mi.
    const bool isQ = tile < 32;
    const float scq = 0.12751744154f;  // log2(e)/sqrt(128)
    u16* outp = isQ ? (Qr + (long)tile * SEQ * HD)
                    : (Kr + (long)(tile - 32) * SEQ * HD);
    float invf[4];
#pragma unroll
    for (int nj = 0; nj < 4; ++nj) {
      float j = (float)(nj * 16 + l15);
      invf[nj] = __builtin_amdgcn_exp2f(-j * (13.287712379549449f / 64.0f));
    }
#pragma unroll
    for (int mi = 0; mi < 4; ++mi) {
      // publish own (bias-added) 16x64 block
#pragma unroll
      for (int nj = 0; nj < 4; ++nj)
#pragma unroll
        for (int r = 0; r < 4; ++r)
          sm.xb[wy][quad * 4 + r][wx * 64 + nj * 16 + l15] = acc[mi][nj][r] + bv[nj];
      __syncthreads();
#pragma unroll
      for (int r = 0; r < 4; ++r) {
        long s = m0 + wy * 64 + mi * 16 + quad * 4 + r;
        float p = (float)pos[s];
        u16* rowp = outp + s * HD;
#pragma unroll
        for (int nj = 0; nj < 4; ++nj) {
          float ang = p * invf[nj];
          float cs, sn;
          __sincosf(ang, &sn, &cs);
          float own = acc[mi][nj][r] + bv[nj];
          float other = sm.xb[wy][quad * 4 + r][(wx ^ 1) * 64 + nj * 16 + l15];
          float o = wx == 0 ? (own * cs - other * sn)   // o1 = x1*cos - x2*sin
                            : (own * cs + other * sn);  // o2 = x2*cos + x1*sin
          if (isQ) o *= scq;
          rowp[wx * 64 + nj * 16 + l15] = f2b(o);
        }
      }
      __syncthreads();
    }
  }
}

// ---------------- flash-style causal GQA attention, paired q-tiles ----------------
__device__ __forceinline__ void attn_tile(
    const bf16x8 q[4], const u16* KsF, const u16* VsF, u16* Psw,
    bool diag, int wq, int quad, int l15, f32x4 Oa[8], f32x4& lacc,
    bf16x8 ones) {
  f32x4 s[4] = {};
#pragma unroll
  for (int ks = 0; ks < 4; ++ks) {
#pragma unroll
    for (int nj = 0; nj < 4; ++nj) {
      bf16x8 bk = *reinterpret_cast<const bf16x8*>(
          &KsF[ks * 2048 + (nj * 16 + l15) * 32 + quad * 8]);
      s[nj] = mfma16(q[ks], bk, s[nj]);
    }
  }
#pragma unroll
  for (int nj = 0; nj < 4; ++nj) {
    int key = nj * 16 + l15;
    int ksw = key >> 5, kc = key & 31;
#pragma unroll
    for (int r = 0; r < 4; ++r) {
      float x = s[nj][r];
      if (diag && key > wq + r) x = -3.0e30f;
      Psw[ksw * 512 + (quad * 4 + r) * 32 + kc] = f2b(__builtin_amdgcn_exp2f(x));
    }
  }
#pragma unroll
  for (int ks = 0; ks < 2; ++ks) {
    bf16x8 ap = *reinterpret_cast<const bf16x8*>(&Psw[ks * 512 + l15 * 32 + quad * 8]);
    lacc = mfma16(ap, ones, lacc);
#pragma unroll
    for (int dj = 0; dj < 8; ++dj) {
      bf16x8 bv = *reinterpret_cast<const bf16x8*>(
          &VsF[ks * 4096 + (dj * 16 + l15) * 32 + quad * 8]);
      Oa[dj] = mfma16(ap, bv, Oa[dj]);
    }
  }
}

__global__ __launch_bounds__(256) void attn_fused(
    const u16* __restrict__ Qr, const u16* __restrict__ Kr,
    const u16* __restrict__ Vt, u16* __restrict__ Ao) {
  __shared__ u16 Ks[4 * 64 * 32];
  __shared__ u16 Vs[2 * 128 * 32];
  __shared__ u16 Ps[4][2 * 16 * 32];
  const int px = blockIdx.x, h = blockIdx.y, kvh = h >> 2;
  const int qtA = px, qtB = (SEQ / 64 - 1) - px;
  const int t = threadIdx.x, w = t >> 6, lane = t & 63;
  const int quad = lane >> 4, l15 = lane & 15;
  const int wq = w * 16 + quad * 4;
  u16* Psw = &Ps[w][0];

  bf16x8 ones;
  {
    union { u16 u[8]; bf16x8 v; } ou;
#pragma unroll
    for (int i = 0; i < 8; ++i) ou.u[i] = 0x3F80;
    ones = ou.v;
  }

  bf16x8 qA[4], qB[4];
  {
    const u16* QgA = Qr + ((long)h * SEQ + qtA * 64) * HD;
    const u16* QgB = Qr + ((long)h * SEQ + qtB * 64) * HD;
    long go = (long)(w * 16 + (lane >> 2)) * HD + (lane & 3) * 8;
#pragma unroll
    for (int j = 0; j < 4; ++j) {
      gl_lds16(QgA + go + j * 32, (char*)Ks + j * 4096 + w * 1024);
      gl_lds16(QgB + go + j * 32, (char*)Vs + j * 4096 + w * 1024);
    }
    __syncthreads();
#pragma unroll
    for (int j = 0; j < 4; ++j) {
      qA[j] = *reinterpret_cast<const bf16x8*>(&Ks[j * 2048 + (w * 16 + l15) * 32 + quad * 8]);
      qB[j] = *reinterpret_cast<const bf16x8*>(&Vs[j * 2048 + (w * 16 + l15) * 32 + quad * 8]);
    }
    __syncthreads();
  }

  f32x4 OaA[8] = {}, OaB[8] = {};
  f32x4 lA = {}, lB = {};
  const u16* Kg0 = Kr + (long)kvh * SEQ * HD;
  const u16* Vg0 = Vt + (long)kvh * HD * SEQ;

  for (int kt = 0; kt <= qtB; ++kt) {
    const int k0 = kt * 64;
    {
      const u16* Kg = Kg0 + (long)k0 * HD;
      long go = (long)(w * 16 + (lane >> 2)) * HD + (lane & 3) * 8;
#pragma unroll
      for (int j = 0; j < 4; ++j)
        gl_lds16(Kg + go + j * 32, (char*)Ks + j * 4096 + w * 1024);
      const u16* Vg = Vg0 + k0;
#pragma unroll
      for (int j = 0; j < 4; ++j) {
        int off = j * 2048 + w * 512 + lane * 8;
        int ks = off >> 12, rem = off & 4095;
        int dd = rem >> 5, kc = rem & 31;
        gl_lds16(Vg + (long)dd * SEQ + ks * 32 + kc, (char*)Vs + j * 4096 + w * 1024);
      }
    }
    __syncthreads();

    attn_tile(qB, Ks, Vs, Psw, kt == qtB, wq, quad, l15, OaB, lB, ones);
    if (kt <= qtA)
      attn_tile(qA, Ks, Vs, Psw, kt == qtA, wq, quad, l15, OaA, lA, ones);

    __syncthreads();
  }

#pragma unroll
  for (int r = 0; r < 4; ++r) {
    float invA = 1.0f / lA[r];
    float invB = 1.0f / lB[r];
    long rowA = (long)(qtA * 64 + w * 16 + quad * 4 + r) * HIDDEN + (long)h * HD;
    long rowB = (long)(qtB * 64 + w * 16 + quad * 4 + r) * HIDDEN + (long)h * HD;
#pragma unroll
    for (int dj = 0; dj < 8; ++dj) {
      Ao[rowA + dj * 16 + l15] = f2b(OaA[dj][r] * invA);
      Ao[rowB + dj * 16 + l15] = f2b(OaB[dj][r] * invB);
    }
  }
}

extern "C" void kernel_launch(void* const* d_in, const int* in_sizes, int n_in,
                              void* d_out, int out_size, void* d_ws, size_t ws_size,
                              hipStream_t stream) {
  const int* positions = (const int*)d_in[0];
  const float* hidden = (const float*)d_in[1];
  const float* Wqkv = (const float*)d_in[2];
  const float* bqkv = (const float*)d_in[3];
  const float* Wproj = (const float*)d_in[4];
  const float* bproj = (const float*)d_in[5];
  float* out = (float*)d_out;
  char* ws = (char*)d_ws;

  u16* Wqt = (u16*)(ws);                  // 6144x4096 bf16   (50331648 B)
  u16* Wpt = (u16*)(ws + 50331648L);      // 4096x4096 bf16   (33554432 B)
  u16* Xb = (u16*)(ws + 83886080L);       // 2048x4096 bf16   (16777216 B)
  u16* Qr = (u16*)(ws + 100663296L);      // 32x2048x128 bf16 (16777216 B)
  u16* Kr = (u16*)(ws + 117440512L);      // 8x2048x128 bf16  (4194304 B)
  u16* Vt = (u16*)(ws + 121634816L);      // 8x128x2048 bf16  (4194304 B)
  u16* Ao = (u16*)(ws + 125829120L);      // 2048x4096 bf16   (16777216 B)

  cvt_bf16<<<8192, 256, 0, stream>>>(hidden, Xb, SEQ * HIDDEN);
  transpose_cvt64<<<dim3(QKVN / 64, HIDDEN / 64), dim3(16, 16), 0, stream>>>(Wqkv, QKVN, Wqt, HIDDEN);
  transpose_cvt64<<<dim3(HIDDEN / 64, HIDDEN / 64), dim3(16, 16), 0, stream>>>(Wproj, HIDDEN, Wpt, HIDDEN);
  gemm_qkv<<<dim3(QKVN / 128, SEQ / 128), 256, 0, stream>>>(Xb, Wqt, bqkv, positions, Qr, Kr, Vt);
  attn_fused<<<dim3(SEQ / 128, NHEADS), 256, 0, stream>>>(Qr, Kr, Vt, Ao);
  gemm_bt_bias<<<dim3(HIDDEN / 128, SEQ / 128), 256, 0, stream>>>(Ao, Wpt, bproj, out, SEQ, HIDDEN, HIDDEN);
}

// Round 5
// 589.567 us; speedup vs baseline: 1.4972x; 1.4972x over previous
//
#include <hip/hip_runtime.h>

#define HIDDEN 4096
#define NHEADS 32
#define NKV 8
#define HD 128
#define KVD 1024
#define QKVN 6144
#define SEQ 2048

typedef unsigned short u16;
typedef __bf16 bf16x8 __attribute__((ext_vector_type(8)));
typedef float f32x4 __attribute__((ext_vector_type(4)));
typedef unsigned short u16x4 __attribute__((ext_vector_type(4)));

__device__ __forceinline__ u16 f2b(float f) {
  union { float f; unsigned u; } v; v.f = f;
  unsigned r = (v.u + 0x7fffu + ((v.u >> 16) & 1u)) >> 16;
  return (u16)r;
}

__device__ __forceinline__ float b2f(u16 b) {
  union { unsigned u; float f; } v; v.u = ((unsigned)b) << 16;
  return v.f;
}

__device__ __forceinline__ void gl_lds16(const void* g, void* l) {
  __builtin_amdgcn_global_load_lds(
      (const __attribute__((address_space(1))) unsigned*)g,
      (__attribute__((address_space(3))) unsigned*)l, 16, 0, 0);
}

__device__ __forceinline__ f32x4 mfma16(bf16x8 a, bf16x8 b, f32x4 c) {
  return __builtin_amdgcn_mfma_f32_16x16x32_bf16(a, b, c, 0, 0, 0);
}

// ---------------- f32 -> bf16 convert ----------------
__global__ void cvt_bf16(const float* __restrict__ x, u16* __restrict__ y, int n) {
  int i = (blockIdx.x * 256 + threadIdx.x) * 4;
  if (i < n) {
    float4 v = *(const float4*)(x + i);
    u16x4 o = {f2b(v.x), f2b(v.y), f2b(v.z), f2b(v.w)};
    *(u16x4*)(y + i) = o;
  }
}

// ---------------- 64x64 tiled transpose + f32->bf16, vectorized ----------------
// out[c][r] = in[r][c].  block (16,16); float4 loads, ushort4 stores.
__global__ void transpose_cvt64(const float* __restrict__ W, long ldW,
                                u16* __restrict__ Wt, long ldT) {
  __shared__ float tile[64][65];
  long c0 = blockIdx.x * 64L, r0 = blockIdx.y * 64L;
  int tx = threadIdx.x, ty = threadIdx.y;
#pragma unroll
  for (int i = 0; i < 4; ++i) {
    float4 v = *(const float4*)(W + (r0 + ty + i * 16) * ldW + c0 + tx * 4);
    tile[ty + i * 16][tx * 4 + 0] = v.x;
    tile[ty + i * 16][tx * 4 + 1] = v.y;
    tile[ty + i * 16][tx * 4 + 2] = v.z;
    tile[ty + i * 16][tx * 4 + 3] = v.w;
  }
  __syncthreads();
#pragma unroll
  for (int i = 0; i < 4; ++i) {
    int c = ty + i * 16;
    u16x4 o = {f2b(tile[tx * 4 + 0][c]), f2b(tile[tx * 4 + 1][c]),
               f2b(tile[tx * 4 + 2][c]), f2b(tile[tx * 4 + 3][c])};
    *(u16x4*)(Wt + (c0 + c) * ldT + r0 + tx * 4) = o;
  }
}

// ---------------- 64x64 tiled transpose, bf16 -> bf16 (for V) ----------------
__global__ void transpose_b16(const u16* __restrict__ W, long ldW,
                              u16* __restrict__ Wt, long ldT) {
  __shared__ float tile[64][65];
  long c0 = blockIdx.x * 64L, r0 = blockIdx.y * 64L;
  int tx = threadIdx.x, ty = threadIdx.y;
#pragma unroll
  for (int i = 0; i < 4; ++i) {
    u16x4 v = *(const u16x4*)(W + (r0 + ty + i * 16) * ldW + c0 + tx * 4);
    tile[ty + i * 16][tx * 4 + 0] = b2f(v.x);
    tile[ty + i * 16][tx * 4 + 1] = b2f(v.y);
    tile[ty + i * 16][tx * 4 + 2] = b2f(v.z);
    tile[ty + i * 16][tx * 4 + 3] = b2f(v.w);
  }
  __syncthreads();
#pragma unroll
  for (int i = 0; i < 4; ++i) {
    int c = ty + i * 16;
    // f2b(b2f(x)) is exact (round-to-nearest of an exactly-representable value)
    u16x4 o = {f2b(tile[tx * 4 + 0][c]), f2b(tile[tx * 4 + 1][c]),
               f2b(tile[tx * 4 + 2][c]), f2b(tile[tx * 4 + 3][c])};
    *(u16x4*)(Wt + (c0 + c) * ldT + r0 + tx * 4) = o;
  }
}

// ---------------- m97-style bf16 GEMM: C = A[M,K] * Bt[N,K]^T + bias (f32 out) ----------------
__global__ __launch_bounds__(256) void gemm_bt_bias(
    const u16* __restrict__ A, const u16* __restrict__ Bt,
    const float* __restrict__ bias, float* __restrict__ C,
    int M, int N, int K) {
  __shared__ u16 As[128 * 32];
  __shared__ u16 Bs[128 * 32];
  const int t = threadIdx.x;
  const int w = t >> 6, lane = t & 63, quad = lane >> 4, l15 = lane & 15;
  const int wy = w >> 1, wx = w & 1;
  const long m0 = blockIdx.y * 128L, n0 = blockIdx.x * 128L;
  f32x4 acc[4][4] = {};
  const u16* Ag = A + (m0 + (t >> 2)) * (long)K + (t & 3) * 8;
  const u16* Bg = Bt + (n0 + (t >> 2)) * (long)K + (t & 3) * 8;
  char* lA0 = (char*)As + w * 1024;
  char* lA1 = (char*)As + 4096 + w * 1024;
  char* lB0 = (char*)Bs + w * 1024;
  char* lB1 = (char*)Bs + 4096 + w * 1024;
  const long k64 = 64L * K;
  for (int k0 = 0; k0 < K; k0 += 32) {
    gl_lds16(Ag + k0, lA0);
    gl_lds16(Ag + k64 + k0, lA1);
    gl_lds16(Bg + k0, lB0);
    gl_lds16(Bg + k64 + k0, lB1);
    __syncthreads();
    bf16x8 af[4], bfr[4];
#pragma unroll
    for (int mi = 0; mi < 4; ++mi)
      af[mi] = *reinterpret_cast<const bf16x8*>(&As[(wy * 64 + mi * 16 + l15) * 32 + quad * 8]);
#pragma unroll
    for (int nj = 0; nj < 4; ++nj)
      bfr[nj] = *reinterpret_cast<const bf16x8*>(&Bs[(wx * 64 + nj * 16 + l15) * 32 + quad * 8]);
#pragma unroll
    for (int mi = 0; mi < 4; ++mi)
#pragma unroll
      for (int nj = 0; nj < 4; ++nj)
        acc[mi][nj] = mfma16(af[mi], bfr[nj], acc[mi][nj]);
    __syncthreads();
  }
#pragma unroll
  for (int mi = 0; mi < 4; ++mi) {
#pragma unroll
    for (int nj = 0; nj < 4; ++nj) {
      long n = n0 + wx * 64 + nj * 16 + l15;
      float bv = bias[n];
      long mrow = m0 + wy * 64 + mi * 16 + quad * 4;
#pragma unroll
      for (int r = 0; r < 4; ++r)
        C[(mrow + r) * (long)N + n] = acc[mi][nj][r] + bv;
    }
  }
}

// ---------------- same GEMM, bf16 output (for QKV intermediate) ----------------
__global__ __launch_bounds__(256) void gemm_bt_bias_b16(
    const u16* __restrict__ A, const u16* __restrict__ Bt,
    const float* __restrict__ bias, u16* __restrict__ C,
    int M, int N, int K) {
  __shared__ u16 As[128 * 32];
  __shared__ u16 Bs[128 * 32];
  const int t = threadIdx.x;
  const int w = t >> 6, lane = t & 63, quad = lane >> 4, l15 = lane & 15;
  const int wy = w >> 1, wx = w & 1;
  const long m0 = blockIdx.y * 128L, n0 = blockIdx.x * 128L;
  f32x4 acc[4][4] = {};
  const u16* Ag = A + (m0 + (t >> 2)) * (long)K + (t & 3) * 8;
  const u16* Bg = Bt + (n0 + (t >> 2)) * (long)K + (t & 3) * 8;
  char* lA0 = (char*)As + w * 1024;
  char* lA1 = (char*)As + 4096 + w * 1024;
  char* lB0 = (char*)Bs + w * 1024;
  char* lB1 = (char*)Bs + 4096 + w * 1024;
  const long k64 = 64L * K;
  for (int k0 = 0; k0 < K; k0 += 32) {
    gl_lds16(Ag + k0, lA0);
    gl_lds16(Ag + k64 + k0, lA1);
    gl_lds16(Bg + k0, lB0);
    gl_lds16(Bg + k64 + k0, lB1);
    __syncthreads();
    bf16x8 af[4], bfr[4];
#pragma unroll
    for (int mi = 0; mi < 4; ++mi)
      af[mi] = *reinterpret_cast<const bf16x8*>(&As[(wy * 64 + mi * 16 + l15) * 32 + quad * 8]);
#pragma unroll
    for (int nj = 0; nj < 4; ++nj)
      bfr[nj] = *reinterpret_cast<const bf16x8*>(&Bs[(wx * 64 + nj * 16 + l15) * 32 + quad * 8]);
#pragma unroll
    for (int mi = 0; mi < 4; ++mi)
#pragma unroll
      for (int nj = 0; nj < 4; ++nj)
        acc[mi][nj] = mfma16(af[mi], bfr[nj], acc[mi][nj]);
    __syncthreads();
  }
#pragma unroll
  for (int mi = 0; mi < 4; ++mi) {
#pragma unroll
    for (int nj = 0; nj < 4; ++nj) {
      long n = n0 + wx * 64 + nj * 16 + l15;
      float bv = bias[n];
      long mrow = m0 + wy * 64 + mi * 16 + quad * 4;
#pragma unroll
      for (int r = 0; r < 4; ++r)
        C[(mrow + r) * (long)N + n] = f2b(acc[mi][nj][r] + bv);
    }
  }
}

// ---------------- RoPE: QKVb bf16 -> Qr (h,s,d)*sc / Kr (kvh,s,d) bf16 ----------------
__global__ void rope_qk(const u16* __restrict__ qkv, const int* __restrict__ pos,
                        u16* __restrict__ Qr, u16* __restrict__ Kr) {
  int s = blockIdx.x;
  int hl = threadIdx.x >> 6;
  int d = threadIdx.x & 63;
  int h = blockIdx.y * 4 + hl;  // 0..39
  float p = (float)pos[s];
  float inv = __builtin_amdgcn_exp2f(-(float)d * (13.287712379549449f / 64.0f));
  float ang = p * inv;
  float cs, sn;
  __sincosf(ang, &sn, &cs);
  long base = (long)s * QKVN + (long)h * HD;
  float x1 = b2f(qkv[base + d]), x2 = b2f(qkv[base + d + 64]);
  float o1 = x1 * cs - x2 * sn, o2 = x2 * cs + x1 * sn;
  if (h < NHEADS) {
    const float sc = 0.12751744154f;  // log2(e)/sqrt(128)
    long ob = ((long)h * SEQ + s) * HD;
    Qr[ob + d] = f2b(o1 * sc);
    Qr[ob + d + 64] = f2b(o2 * sc);
  } else {
    long ob = ((long)(h - NHEADS) * SEQ + s) * HD;
    Kr[ob + d] = f2b(o1);
    Kr[ob + d + 64] = f2b(o2);
  }
}

// ---------------- flash-style causal GQA attention, paired q-tiles ----------------
__device__ __forceinline__ void attn_tile(
    const bf16x8 q[4], const u16* KsF, const u16* VsF, u16* Psw,
    bool diag, int wq, int quad, int l15, f32x4 Oa[8], f32x4& lacc,
    bf16x8 ones) {
  f32x4 s[4] = {};
#pragma unroll
  for (int ks = 0; ks < 4; ++ks) {
#pragma unroll
    for (int nj = 0; nj < 4; ++nj) {
      bf16x8 bk = *reinterpret_cast<const bf16x8*>(
          &KsF[ks * 2048 + (nj * 16 + l15) * 32 + quad * 8]);
      s[nj] = mfma16(q[ks], bk, s[nj]);
    }
  }
#pragma unroll
  for (int nj = 0; nj < 4; ++nj) {
    int key = nj * 16 + l15;
    int ksw = key >> 5, kc = key & 31;
#pragma unroll
    for (int r = 0; r < 4; ++r) {
      float x = s[nj][r];
      if (diag && key > wq + r) x = -3.0e30f;
      Psw[ksw * 512 + (quad * 4 + r) * 32 + kc] = f2b(__builtin_amdgcn_exp2f(x));
    }
  }
#pragma unroll
  for (int ks = 0; ks < 2; ++ks) {
    bf16x8 ap = *reinterpret_cast<const bf16x8*>(&Psw[ks * 512 + l15 * 32 + quad * 8]);
    lacc = mfma16(ap, ones, lacc);
#pragma unroll
    for (int dj = 0; dj < 8; ++dj) {
      bf16x8 bv = *reinterpret_cast<const bf16x8*>(
          &VsF[ks * 4096 + (dj * 16 + l15) * 32 + quad * 8]);
      Oa[dj] = mfma16(ap, bv, Oa[dj]);
    }
  }
}

__global__ __launch_bounds__(256) void attn_fused(
    const u16* __restrict__ Qr, const u16* __restrict__ Kr,
    const u16* __restrict__ Vt, u16* __restrict__ Ao) {
  __shared__ u16 Ks[4 * 64 * 32];
  __shared__ u16 Vs[2 * 128 * 32];
  __shared__ u16 Ps[4][2 * 16 * 32];
  const int px = blockIdx.x, h = blockIdx.y, kvh = h >> 2;
  const int qtA = px, qtB = (SEQ / 64 - 1) - px;
  const int t = threadIdx.x, w = t >> 6, lane = t & 63;
  const int quad = lane >> 4, l15 = lane & 15;
  const int wq = w * 16 + quad * 4;
  u16* Psw = &Ps[w][0];

  bf16x8 ones;
  {
    union { u16 u[8]; bf16x8 v; } ou;
#pragma unroll
    for (int i = 0; i < 8; ++i) ou.u[i] = 0x3F80;
    ones = ou.v;
  }

  bf16x8 qA[4], qB[4];
  {
    const u16* QgA = Qr + ((long)h * SEQ + qtA * 64) * HD;
    const u16* QgB = Qr + ((long)h * SEQ + qtB * 64) * HD;
    long go = (long)(w * 16 + (lane >> 2)) * HD + (lane & 3) * 8;
#pragma unroll
    for (int j = 0; j < 4; ++j) {
      gl_lds16(QgA + go + j * 32, (char*)Ks + j * 4096 + w * 1024);
      gl_lds16(QgB + go + j * 32, (char*)Vs + j * 4096 + w * 1024);
    }
    __syncthreads();
#pragma unroll
    for (int j = 0; j < 4; ++j) {
      qA[j] = *reinterpret_cast<const bf16x8*>(&Ks[j * 2048 + (w * 16 + l15) * 32 + quad * 8]);
      qB[j] = *reinterpret_cast<const bf16x8*>(&Vs[j * 2048 + (w * 16 + l15) * 32 + quad * 8]);
    }
    __syncthreads();
  }

  f32x4 OaA[8] = {}, OaB[8] = {};
  f32x4 lA = {}, lB = {};
  const u16* Kg0 = Kr + (long)kvh * SEQ * HD;
  const u16* Vg0 = Vt + (long)kvh * HD * SEQ;

  for (int kt = 0; kt <= qtB; ++kt) {
    const int k0 = kt * 64;
    {
      const u16* Kg = Kg0 + (long)k0 * HD;
      long go = (long)(w * 16 + (lane >> 2)) * HD + (lane & 3) * 8;
#pragma unroll
      for (int j = 0; j < 4; ++j)
        gl_lds16(Kg + go + j * 32, (char*)Ks + j * 4096 + w * 1024);
      const u16* Vg = Vg0 + k0;
#pragma unroll
      for (int j = 0; j < 4; ++j) {
        int off = j * 2048 + w * 512 + lane * 8;
        int ks = off >> 12, rem = off & 4095;
        int dd = rem >> 5, kc = rem & 31;
        gl_lds16(Vg + (long)dd * SEQ + ks * 32 + kc, (char*)Vs + j * 4096 + w * 1024);
      }
    }
    __syncthreads();

    attn_tile(qB, Ks, Vs, Psw, kt == qtB, wq, quad, l15, OaB, lB, ones);
    if (kt <= qtA)
      attn_tile(qA, Ks, Vs, Psw, kt == qtA, wq, quad, l15, OaA, lA, ones);

    __syncthreads();
  }

#pragma unroll
  for (int r = 0; r < 4; ++r) {
    float invA = 1.0f / lA[r];
    float invB = 1.0f / lB[r];
    long rowA = (long)(qtA * 64 + w * 16 + quad * 4 + r) * HIDDEN + (long)h * HD;
    long rowB = (long)(qtB * 64 + w * 16 + quad * 4 + r) * HIDDEN + (long)h * HD;
#pragma unroll
    for (int dj = 0; dj < 8; ++dj) {
      Ao[rowA + dj * 16 + l15] = f2b(OaA[dj][r] * invA);
      Ao[rowB + dj * 16 + l15] = f2b(OaB[dj][r] * invB);
    }
  }
}

extern "C" void kernel_launch(void* const* d_in, const int* in_sizes, int n_in,
                              void* d_out, int out_size, void* d_ws, size_t ws_size,
                              hipStream_t stream) {
  const int* positions = (const int*)d_in[0];
  const float* hidden = (const float*)d_in[1];
  const float* Wqkv = (const float*)d_in[2];
  const float* bqkv = (const float*)d_in[3];
  const float* Wproj = (const float*)d_in[4];
  const float* bproj = (const float*)d_in[5];
  float* out = (float*)d_out;
  char* ws = (char*)d_ws;

  u16* Wqt = (u16*)(ws);                  // 6144x4096 bf16   (50331648 B)
  u16* Wpt = (u16*)(ws + 50331648L);      // 4096x4096 bf16   (33554432 B)
  u16* Xb = (u16*)(ws + 83886080L);       // 2048x4096 bf16   (16777216 B)
  u16* QKVb = (u16*)(ws + 100663296L);    // 2048x6144 bf16   (25165824 B)
  u16* Qr = (u16*)(ws + 125829120L);      // 32x2048x128 bf16 (16777216 B)
  u16* Kr = (u16*)(ws + 142606336L);      // 8x2048x128 bf16  (4194304 B)
  u16* Vt = (u16*)(ws + 146800640L);      // 8x128x2048 bf16  (4194304 B)
  u16* Ao = (u16*)(ws + 150994944L);      // 2048x4096 bf16   (16777216 B)
  // total ws use: 167772160 B

  cvt_bf16<<<8192, 256, 0, stream>>>(hidden, Xb, SEQ * HIDDEN);
  transpose_cvt64<<<dim3(QKVN / 64, HIDDEN / 64), dim3(16, 16), 0, stream>>>(Wqkv, QKVN, Wqt, HIDDEN);
  transpose_cvt64<<<dim3(HIDDEN / 64, HIDDEN / 64), dim3(16, 16), 0, stream>>>(Wproj, HIDDEN, Wpt, HIDDEN);
  gemm_bt_bias_b16<<<dim3(QKVN / 128, SEQ / 128), 256, 0, stream>>>(Xb, Wqt, bqkv, QKVb, SEQ, QKVN, HIDDEN);
  rope_qk<<<dim3(SEQ, 10), 256, 0, stream>>>(QKVb, positions, Qr, Kr);
  transpose_b16<<<dim3(KVD / 64, SEQ / 64), dim3(16, 16), 0, stream>>>(QKVb + 5120, QKVN, Vt, SEQ);
  attn_fused<<<dim3(SEQ / 128, NHEADS), 256, 0, stream>>>(Qr, Kr, Vt, Ao);
  gemm_bt_bias<<<dim3(HIDDEN / 128, SEQ / 128), 256, 0, stream>>>(Ao, Wpt, bproj, out, SEQ, HIDDEN, HIDDEN);
}